// Round 1
// baseline (1187.913 us; speedup 1.0000x reference)
//
#include <hip/hip_runtime.h>
#include <math.h>

// Fused spectral Wirtinger-derivative kernel.
// One 1024-thread block per (b,C) image; whole 128x128 complex image in LDS.
// Each 128-point FFT: 8 threads x 16 register points, 16x8 Cooley-Tukey,
// single LDS exchange per 1-D transform. XOR-swizzled exchange slots keep
// LDS bank conflicts <=2-way (free on gfx950).
//
// R1 lesson (rocprof): launch_bounds(1024,4) did NOT raise the VGPR budget —
// dynamic LDS hides the 1-block/CU limit, so the compiler targeted 8 waves/EU
// and allocated 64 VGPRs -> ~1.2GB/dispatch scratch spill (FETCH 549MB vs
// 67MB ideal). Fixes here:
//  (a) amdgpu_waves_per_eu(4,4) pins occupancy to 4 waves/EU (the LDS-imposed
//      reality), giving the allocator the full 128 VGPRs.
//  (b) No 32-float array is held live across any FFT call any more:
//      - B1 (col-IFFT of W*F) is staged to GLOBAL (out_la/out_ph, overwritten
//        with final values later) instead of regs->LDS later.
//      - R2b (d2x0 rows) runs FIRST from LDS-staged B2; dy is staged to
//        out_lt/out_ps (group-private rows, L2-hot).
//      - R2a reloads B1 rows from global, computes dx, and one fused output
//        loop reloads dy per-point and overwrites all staging with finals.
//      Peak live state ~96 data floats + overhead -> fits 128 VGPRs.

#define LSTR 132                 // LDS row stride in floats (+4 pad: 2-way banks)
#define SHBYTES (2 * 128 * LSTR * 4)

struct cf { float re, im; };
__device__ __forceinline__ cf cmul(cf a, cf b) {
    return { a.re * b.re - a.im * b.im, a.re * b.im + a.im * b.re };
}
__device__ __forceinline__ cf cadd(cf a, cf b) { return { a.re + b.re, a.im + b.im }; }
__device__ __forceinline__ cf csub(cf a, cf b) { return { a.re - b.re, a.im - b.im }; }

// bit-reversal tables (involutions)
__device__ constexpr int BR4[16] = {0,8,4,12,2,10,6,14,1,9,5,13,3,11,7,15};
__device__ constexpr int BR3[8]  = {0,4,2,6,1,5,3,7};

// 16-point DFT, radix-2 DIF, natural in, bit-reversed out: R[k] = r[BR4[k]].
template <int SGN>
__device__ __forceinline__ void dft16(cf* r) {
    const float C16[8] = {1.f, 0.92387953251f, 0.70710678119f, 0.38268343236f,
                          0.f, -0.38268343236f, -0.70710678119f, -0.92387953251f};
    const float S16[8] = {0.f, 0.38268343236f, 0.70710678119f, 0.92387953251f,
                          1.f, 0.92387953251f, 0.70710678119f, 0.38268343236f};
    const float C8[4] = {1.f, 0.70710678119f, 0.f, -0.70710678119f};
    const float S8[4] = {0.f, 0.70710678119f, 1.f, 0.70710678119f};
#pragma unroll
    for (int j = 0; j < 8; j++) {
        cf u = r[j], v = r[j + 8];
        r[j] = cadd(u, v);
        cf d = csub(u, v);
        cf w = { C16[j], (float)SGN * S16[j] };
        r[j + 8] = cmul(d, w);
    }
#pragma unroll
    for (int b = 0; b < 16; b += 8)
#pragma unroll
        for (int j = 0; j < 4; j++) {
            cf u = r[b + j], v = r[b + j + 4];
            r[b + j] = cadd(u, v);
            cf d = csub(u, v);
            cf w = { C8[j], (float)SGN * S8[j] };
            r[b + j + 4] = cmul(d, w);
        }
#pragma unroll
    for (int b = 0; b < 16; b += 4) {
        cf u = r[b], v = r[b + 2];
        r[b] = cadd(u, v); r[b + 2] = csub(u, v);
        u = r[b + 1]; v = r[b + 3];
        r[b + 1] = cadd(u, v);
        cf d = csub(u, v);
        r[b + 3] = { (float)(-SGN) * d.im, (float)SGN * d.re };  // d * (0,SGN)
    }
#pragma unroll
    for (int b = 0; b < 16; b += 2) {
        cf u = r[b], v = r[b + 1];
        r[b] = cadd(u, v); r[b + 1] = csub(u, v);
    }
}

// 8-point DFT, natural in, bit-reversed out: R[k] = r[BR3[k]].
template <int SGN>
__device__ __forceinline__ void dft8(cf* r) {
    const float C8[4] = {1.f, 0.70710678119f, 0.f, -0.70710678119f};
    const float S8[4] = {0.f, 0.70710678119f, 1.f, 0.70710678119f};
#pragma unroll
    for (int j = 0; j < 4; j++) {
        cf u = r[j], v = r[j + 4];
        r[j] = cadd(u, v);
        cf d = csub(u, v);
        cf w = { C8[j], (float)SGN * S8[j] };
        r[j + 4] = cmul(d, w);
    }
#pragma unroll
    for (int b = 0; b < 8; b += 4) {
        cf u = r[b], v = r[b + 2];
        r[b] = cadd(u, v); r[b + 2] = csub(u, v);
        u = r[b + 1]; v = r[b + 3];
        r[b + 1] = cadd(u, v);
        cf d = csub(u, v);
        r[b + 3] = { (float)(-SGN) * d.im, (float)SGN * d.re };
    }
#pragma unroll
    for (int b = 0; b < 8; b += 2) {
        cf u = r[b], v = r[b + 1];
        r[b] = cadd(u, v); r[b + 1] = csub(u, v);
    }
}

// 128-pt FFT "A": input natural ownership r[j] = x[8j+t]; output
// o[8d+k2] = X[t + 8d + 16*k2]. One LDS exchange (region: base + slot*stride).
template <int SGN>
__device__ __forceinline__ void fft128A(cf* r, cf* o, int t,
                                        float* Mre, float* Mim, int base, int stride) {
    dft16<SGN>(r);
    float sv, cv;
    __sincosf(6.283185307179586f * (float)t * (1.0f / 128.0f), &sv, &cv);
    cf w = { cv, (float)SGN * sv };
    cf wp = w;
#pragma unroll
    for (int k = 1; k < 16; k++) {          // k=0 twiddle is 1
        int p = BR4[k];
        r[p] = cmul(r[p], wp);
        wp = cmul(wp, w);
    }
#pragma unroll
    for (int k = 0; k < 16; k++) {
        int slot = 8 * k + (t ^ (k & 7));
        int a = base + slot * stride;
        Mre[a] = r[BR4[k]].re;
        Mim[a] = r[BR4[k]].im;
    }
    __syncthreads();
    cf s0[8], s1[8];
#pragma unroll
    for (int n = 0; n < 8; n++) {
        int a0 = base + (8 * t + (n ^ t)) * stride;
        int a1 = base + (8 * t + 64 + (n ^ t)) * stride;
        s0[n] = { Mre[a0], Mim[a0] };
        s1[n] = { Mre[a1], Mim[a1] };
    }
    dft8<SGN>(s0);
    dft8<SGN>(s1);
#pragma unroll
    for (int k2 = 0; k2 < 8; k2++) {
        o[k2]     = s0[BR3[k2]];
        o[8 + k2] = s1[BR3[k2]];
    }
}

// 128-pt FFT "B": input A-ownership r[8d+k2] = Y[t + 8d + 16*k2]; output
// natural ownership o[m1] = z[8*m1 + t]. One LDS exchange.
template <int SGN>
__device__ __forceinline__ void fft128B(cf* r, cf* o, int t,
                                        float* Mre, float* Mim, int base, int stride) {
    dft8<SGN>(r);       // C[t][mu]   at r[BR3[mu]]
    dft8<SGN>(r + 8);   // C[t+8][mu] at r[8+BR3[mu]]
    float sv, cv;
    __sincosf(6.283185307179586f * (float)t * (1.0f / 128.0f), &sv, &cv);
    cf w0 = { cv, (float)SGN * sv };                               // e^{SGN 2pi i t/128}
    const cf e8 = { 0.92387953251f, (float)SGN * 0.38268343236f }; // e^{SGN 2pi i 8/128}
    cf w1 = cmul(w0, e8);
    cf wp0 = w0, wp1 = w1;
#pragma unroll
    for (int mu = 1; mu < 8; mu++) {        // mu=0 twiddle is 1
        r[BR3[mu]]     = cmul(r[BR3[mu]], wp0);
        r[8 + BR3[mu]] = cmul(r[8 + BR3[mu]], wp1);
        wp0 = cmul(wp0, w0);
        wp1 = cmul(wp1, w1);
    }
#pragma unroll
    for (int mu = 0; mu < 8; mu++) {
        int aA = base + (16 * mu + (t ^ mu)) * stride;
        int aB = base + (16 * mu + ((t ^ mu) + 8)) * stride;   // (t+8)^mu = (t^mu)+8
        Mre[aA] = r[BR3[mu]].re;     Mim[aA] = r[BR3[mu]].im;
        Mre[aB] = r[8 + BR3[mu]].re; Mim[aB] = r[8 + BR3[mu]].im;
    }
    __syncthreads();
    cf q[16];
#pragma unroll
    for (int k = 0; k < 16; k++) {
        int a = base + (16 * t + (k ^ t)) * stride;
        q[k] = { Mre[a], Mim[a] };
    }
    dft16<SGN>(q);       // z[t + 8*m1] = q[BR4[m1]]
#pragma unroll
    for (int m1 = 0; m1 < 16; m1++) o[m1] = q[BR4[m1]];
}

__global__ __launch_bounds__(1024) __attribute__((amdgpu_waves_per_eu(4, 4)))
void operators_52261162057769_kernel(
        const float* __restrict__ x, const float* __restrict__ df,
        const float* __restrict__ d2f, float* __restrict__ out,
        long outn, int nch) {
    extern __shared__ float lds[];
    float* Mre = lds;
    float* Mim = lds + 128 * LSTR;

    const int tid = threadIdx.x;
    const int g = tid >> 3;     // row (R-phases) / column (C-phase) id
    const int t = tid & 7;      // lane within 8-thread FFT group
    const int im = blockIdx.x;
    const int ch = im % nch;
    const long base = (long)im * 16384L;

    // per-channel params (uniform across block)
    const float df0 = df[2 * ch], df1 = df[2 * ch + 1];
    const float ea = expf(df0);
    const cf dfc = { ea * cosf(df1), ea * sinf(df1) };
    const cf d2fc = { d2f[2 * ch], d2f[2 * ch + 1] };
    const cf df2 = cmul(dfc, dfc);
    const float df2m = 1.0f / (df2.re * df2.re + df2.im * df2.im);
    const cf inv_df2 = { df2.re * df2m, -df2.im * df2m };   // 1/dfc^2

    float* out_h  = out;
    float* out_la = out + outn;       // staging: B1.re   -> final lnAlpha
    float* out_ph = out + 2 * outn;   // staging: B1.im   -> final Phi
    float* out_lt = out + 3 * outn;   // staging: dy.re   -> final lnTau
    float* out_ps = out + 4 * outn;   // staging: dy.im   -> final Psi

    cf r[16], o[16];

    // ---- Phase R1: forward FFT along rows (axis 1) -> H in LDS ----
#pragma unroll
    for (int j = 0; j < 16; j++) {
        r[j].re = x[base + g * 128 + 8 * j + t];
        r[j].im = 0.f;
    }
    fft128A<-1>(r, o, t, Mre, Mim, g * LSTR, 1);
#pragma unroll
    for (int i = 0; i < 16; i++) {
        int col = t + 8 * (i >> 3) + 16 * (i & 7);
        Mre[g * LSTR + col] = o[i].re;
        Mim[g * LSTR + col] = o[i].im;
    }
    __syncthreads();

    // ---- Phase C: per column c=g: fwd FFT (axis 0), multiply by W, W^2,
    //      two inverse FFTs (axis 0). B1 -> global staging, B2 -> LDS. ----
    const int c = g;
#pragma unroll
    for (int j = 0; j < 16; j++) {
        int a = (8 * j + t) * LSTR + c;
        r[j] = { Mre[a], Mim[a] };
    }
    fft128A<-1>(r, o, t, Mre, Mim, c, LSTR);

    const float kc = (c < 64) ? (float)c : (float)(c - 128);
    cf g1[16], g2[16];
#pragma unroll
    for (int i = 0; i < 16; i++) {
        int d = i >> 3, k2 = i & 7;
        int k = t + 8 * d + 16 * k2;
        float kr = (k2 < 4) ? (float)k : (float)(k - 128);  // k>=64 <=> k2>=4
        cf W = { -kc, kr };                                 // i*k_r - k_c
        cf P = cmul(W, o[i]);
        cf Q = cmul(W, P);
        const float invZ = 1.0f / 16384.0f;                 // ifft2 normalization
        g1[i] = { P.re * invZ, P.im * invZ };
        g2[i] = { Q.re * invZ, Q.im * invZ };
    }
    cf b2[16];
    fft128B<1>(g2, b2, t, Mre, Mim, c, LSTR);   // B2 = IFFT0(W^2 F)
    {
        cf b1[16];
        fft128B<1>(g1, b1, t, Mre, Mim, c, LSTR);  // B1 = IFFT0(W F)
        // stage B1 -> global (natural layout); overwritten with finals in R2a
#pragma unroll
        for (int m1 = 0; m1 < 16; m1++) {
            long idx = base + (long)((8 * m1 + t) * 128 + c);
            out_la[idx] = b1[m1].re;
            out_ph[idx] = b1[m1].im;
        }
    }
    // B2 -> LDS natural (column-private writes)
#pragma unroll
    for (int m1 = 0; m1 < 16; m1++) {
        int a = (8 * m1 + t) * LSTR + c;
        Mre[a] = b2[m1].re; Mim[a] = b2[m1].im;
    }
    __syncthreads();   // also drains the B1 staging stores (vmcnt(0) + barrier)

    // ---- Phase R2b: inverse FFT along rows of B2 -> dy; stage dy ----
#pragma unroll
    for (int j = 0; j < 16; j++) {
        int a = g * LSTR + 8 * j + t;
        r[j] = { Mre[a], Mim[a] };
    }
    cf dy[16];
    fft128A<1>(r, dy, t, Mre, Mim, g * LSTR, 1);
#pragma unroll
    for (int i = 0; i < 16; i++) {
        int col = t + 8 * (i >> 3) + 16 * (i & 7);
        long idx = base + g * 128 + col;
        out_lt[idx] = dy[i].re;    // group-private row; reloaded below (L2-hot)
        out_ps[idx] = dy[i].im;
    }

    // ---- Phase R2a: inverse FFT along rows of B1 (from global staging) ----
    // Visibility: staging writes happened before the __syncthreads above, and
    // R2b's fft128A contains another barrier. Lines were never read into L1
    // before, so first read fetches from L2. Same CU throughout.
#pragma unroll
    for (int j = 0; j < 16; j++) {
        long idx = base + g * 128 + 8 * j + t;
        r[j] = { out_la[idx], out_ph[idx] };
    }
    cf dx[16];
    fft128A<1>(r, dx, t, Mre, Mim, g * LSTR, 1);

    // ---- Fused epilogue: all 5 outputs; overwrites all staging ----
#pragma unroll
    for (int i = 0; i < 16; i++) {
        int col = t + 8 * (i >> 3) + 16 * (i & 7);
        long idx = base + g * 128 + col;
        // reload dy early (same lane wrote it; >=1 barrier since -> no forwarding)
        float yr = out_lt[idx], yi = out_ps[idx];

        float xr = dx[i].re, xi = dx[i].im;
        float h = xr * xr + xi * xi;
        out_h[idx] = h;
        bool valid = sqrtf(h) >= 0.001f;
        float sxr = valid ? xr : 1.f;
        float sxi = valid ? xi : 0.f;
        float hs  = valid ? h : 1.f;
        float ih  = 1.f / hs;
        // a2 = dfc * conj(dxs) / |dxs|^2
        float a2r = (dfc.re * sxr + dfc.im * sxi) * ih;
        float a2i = (dfc.im * sxr - dfc.re * sxi) * ih;
        float la = 0.5f * __logf(a2r * a2r + a2i * a2i);
        la = fminf(fmaxf(la, -3.f), 3.f);
        out_la[idx] = valid ? la : 0.f;
        float ph = atan2f(a2i, a2r);
        out_ph[idx] = valid ? ph : 0.f;

        // w2 = dxs^2
        float w2r = sxr * sxr - sxi * sxi;
        float w2i = 2.f * sxr * sxi;
        // an = 0.5*(d2x0 - d2fc*w2/dfc^2) * dfc * conj(w2) / hs^2
        cf t1 = cmul(d2fc, { w2r, w2i });
        cf u  = cmul(t1, inv_df2);
        cf v  = { yr - u.re, yi - u.im };
        cf t2 = cmul(v, dfc);
        cf t3 = cmul(t2, { w2r, -w2i });
        float s = 0.5f * ih * ih;
        float anr = t3.re * s, ani = t3.im * s;
        float m2 = anr * anr + ani * ani;
        bool tm = valid && (sqrtf(m2) >= 0.001f);
        float lt = 0.5f * __logf(m2);
        lt = fminf(fmaxf(lt, -2.5902671654f), 3.f);
        out_lt[idx] = tm ? lt : -6.9077552790f;
        float ps = atan2f(ani, anr);
        out_ps[idx] = tm ? ps : 0.f;
    }
}

extern "C" void kernel_launch(void* const* d_in, const int* in_sizes, int n_in,
                              void* d_out, int out_size, void* d_ws, size_t ws_size,
                              hipStream_t stream) {
    const float* x   = (const float*)d_in[0];
    const float* df  = (const float*)d_in[1];
    const float* d2f = (const float*)d_in[2];
    float* out = (float*)d_out;

    const int n_img = in_sizes[0] / 16384;       // b*C = 1024
    const int nch   = in_sizes[1] / 2;           // C = 64
    const long outn = (long)out_size / 5;

    // >64KB dynamic LDS needs the attribute; host-side, graph-capture safe.
    hipFuncSetAttribute((const void*)operators_52261162057769_kernel,
                        hipFuncAttributeMaxDynamicSharedMemorySize, SHBYTES);

    operators_52261162057769_kernel<<<dim3(n_img), dim3(1024), SHBYTES, stream>>>(
        x, df, d2f, out, outn, nch);
}

// Round 2
// 1124.901 us; speedup vs baseline: 1.0560x; 1.0560x over previous
//
#include <hip/hip_runtime.h>
#include <math.h>

// Fused spectral Wirtinger-derivative kernel, v3: shuffle-exchange FFTs.
//
// R0/R1 lesson: the VGPR budget is stuck at 64 (dynamic LDS defeats both
// __launch_bounds__(1024,4) and amdgpu_waves_per_eu(4,4)); holding any extra
// 16-cf array across an FFT spills ~1GB/dispatch to scratch. So: design for
// 64 VGPRs.
//
// Each 8-thread FFT group is contained in one wave, so the 128-pt FFT's
// exchange (two 8x8 complex transposes) is done with the 3-stage shfl_xor
// butterfly register transpose — NO LDS use, NO barrier. LDS becomes pure
// image storage:
//   R1:  x rows -FFT-> H in LDS
//   C1:  per col: FFT, *W/16384, IFFT -> B1 col (overwrites own H col)
//   R2a: B1 rows (read-only!) -IFFT-> dx; outputs h/lnAlpha/Phi; stash dx
//   C2:  per col of intact B1: FFT (=W*F/128), *W/128, IFFT -> B2 col
//   R2b: B2 rows -IFFT-> dy; reload dx stash; outputs lnTau/Psi
// Peak live state = one 16-cf array + transpose temps ~= 50 VGPRs -> no spill.
// Only 4 block barriers; only staging traffic is the dx stash (2 floats/pt).

#define LSTR 132                 // LDS row stride in floats (2-way banks max)
#define SHBYTES (2 * 128 * LSTR * 4)

struct cf { float re, im; };
__device__ __forceinline__ cf cmul(cf a, cf b) {
    return { a.re * b.re - a.im * b.im, a.re * b.im + a.im * b.re };
}
__device__ __forceinline__ cf cadd(cf a, cf b) { return { a.re + b.re, a.im + b.im }; }
__device__ __forceinline__ cf csub(cf a, cf b) { return { a.re - b.re, a.im - b.im }; }

// bit-reversal tables (involutions)
__device__ constexpr int BR4[16] = {0,8,4,12,2,10,6,14,1,9,5,13,3,11,7,15};
__device__ constexpr int BR3[8]  = {0,4,2,6,1,5,3,7};

// 16-point DFT, radix-2 DIF, natural in, bit-reversed out: R[k] = r[BR4[k]].
template <int SGN>
__device__ __forceinline__ void dft16(cf* r) {
    const float C16[8] = {1.f, 0.92387953251f, 0.70710678119f, 0.38268343236f,
                          0.f, -0.38268343236f, -0.70710678119f, -0.92387953251f};
    const float S16[8] = {0.f, 0.38268343236f, 0.70710678119f, 0.92387953251f,
                          1.f, 0.92387953251f, 0.70710678119f, 0.38268343236f};
    const float C8[4] = {1.f, 0.70710678119f, 0.f, -0.70710678119f};
    const float S8[4] = {0.f, 0.70710678119f, 1.f, 0.70710678119f};
#pragma unroll
    for (int j = 0; j < 8; j++) {
        cf u = r[j], v = r[j + 8];
        r[j] = cadd(u, v);
        cf d = csub(u, v);
        cf w = { C16[j], (float)SGN * S16[j] };
        r[j + 8] = cmul(d, w);
    }
#pragma unroll
    for (int b = 0; b < 16; b += 8)
#pragma unroll
        for (int j = 0; j < 4; j++) {
            cf u = r[b + j], v = r[b + j + 4];
            r[b + j] = cadd(u, v);
            cf d = csub(u, v);
            cf w = { C8[j], (float)SGN * S8[j] };
            r[b + j + 4] = cmul(d, w);
        }
#pragma unroll
    for (int b = 0; b < 16; b += 4) {
        cf u = r[b], v = r[b + 2];
        r[b] = cadd(u, v); r[b + 2] = csub(u, v);
        u = r[b + 1]; v = r[b + 3];
        r[b + 1] = cadd(u, v);
        cf d = csub(u, v);
        r[b + 3] = { (float)(-SGN) * d.im, (float)SGN * d.re };  // d * (0,SGN)
    }
#pragma unroll
    for (int b = 0; b < 16; b += 2) {
        cf u = r[b], v = r[b + 1];
        r[b] = cadd(u, v); r[b + 1] = csub(u, v);
    }
}

// 8-point DFT, natural in, bit-reversed out: R[k] = r[BR3[k]].
template <int SGN>
__device__ __forceinline__ void dft8(cf* r) {
    const float C8[4] = {1.f, 0.70710678119f, 0.f, -0.70710678119f};
    const float S8[4] = {0.f, 0.70710678119f, 1.f, 0.70710678119f};
#pragma unroll
    for (int j = 0; j < 4; j++) {
        cf u = r[j], v = r[j + 4];
        r[j] = cadd(u, v);
        cf d = csub(u, v);
        cf w = { C8[j], (float)SGN * S8[j] };
        r[j + 4] = cmul(d, w);
    }
#pragma unroll
    for (int b = 0; b < 8; b += 4) {
        cf u = r[b], v = r[b + 2];
        r[b] = cadd(u, v); r[b + 2] = csub(u, v);
        u = r[b + 1]; v = r[b + 3];
        r[b + 1] = cadd(u, v);
        cf d = csub(u, v);
        r[b + 3] = { (float)(-SGN) * d.im, (float)SGN * d.re };
    }
#pragma unroll
    for (int b = 0; b < 8; b += 2) {
        cf u = r[b], v = r[b + 1];
        r[b] = cadd(u, v); r[b + 1] = csub(u, v);
    }
}

// 8x8 complex register transpose across the 8 lanes of a group (t = lane&7):
// after the call, a[j]@t == old a[t]@j. 3-stage shfl_xor butterfly; masks
// 1/2/4 stay within the 8-lane group (groups are wave-contained).
__device__ __forceinline__ void xpose8(cf* a, int t) {
#pragma unroll
    for (int b = 1; b < 8; b <<= 1) {
#pragma unroll
        for (int j = 0; j < 8; j++) {
            if (j & b) continue;           // compile-time: pairs (j, j|b)
            cf lo = a[j], hi = a[j | b];
            const bool up = (t & b) != 0;
            float sr = up ? lo.re : hi.re;
            float si = up ? lo.im : hi.im;
            float rr = __shfl_xor(sr, b);
            float ri = __shfl_xor(si, b);
            a[j].re     = up ? rr : lo.re;
            a[j].im     = up ? ri : lo.im;
            a[j | b].re = up ? hi.re : rr;
            a[j | b].im = up ? hi.im : ri;
        }
    }
}

// 128-pt FFT "A": input natural ownership r[j] = x[8j+t]; output
// o[8d+k2] = X[t + 8d + 16*k2]. Register-only exchange.
template <int SGN>
__device__ __forceinline__ void fft128A(cf* r, cf* o, int t) {
    dft16<SGN>(r);
    float sv, cv;
    __sincosf(6.283185307179586f * (float)t * (1.0f / 128.0f), &sv, &cv);
    cf w = { cv, (float)SGN * sv };
    cf wp = w;
#pragma unroll
    for (int k = 1; k < 16; k++) {          // k=0 twiddle is 1
        int p = BR4[k];
        r[p] = cmul(r[p], wp);
        wp = cmul(wp, w);
    }
    // value at logical slot (k, t) is r[BR4[k]]; s0[n] = slot(k=t)@lane n,
    // s1[n] = slot(k=t+8)@lane n  ->  two 8x8 transposes.
    cf a[8], b[8];
#pragma unroll
    for (int m = 0; m < 8; m++) { a[m] = r[BR4[m]]; b[m] = r[BR4[m + 8]]; }
    xpose8(a, t);
    xpose8(b, t);
    dft8<SGN>(a);
    dft8<SGN>(b);
#pragma unroll
    for (int k2 = 0; k2 < 8; k2++) {
        o[k2]     = a[BR3[k2]];
        o[8 + k2] = b[BR3[k2]];
    }
}

// 128-pt FFT "B": input A-ownership r[8d+k2] = Y[t + 8d + 16*k2]; output
// natural ownership o[m1] = z[8*m1 + t]. Register-only exchange.
template <int SGN>
__device__ __forceinline__ void fft128B(cf* r, cf* o, int t) {
    dft8<SGN>(r);       // C[t][mu]   at r[BR3[mu]]
    dft8<SGN>(r + 8);   // C[t+8][mu] at r[8+BR3[mu]]
    float sv, cv;
    __sincosf(6.283185307179586f * (float)t * (1.0f / 128.0f), &sv, &cv);
    cf w0 = { cv, (float)SGN * sv };                               // e^{SGN 2pi i t/128}
    const cf e8 = { 0.92387953251f, (float)SGN * 0.38268343236f }; // e^{SGN 2pi i 8/128}
    cf w1 = cmul(w0, e8);
    cf wp0 = w0, wp1 = w1;
#pragma unroll
    for (int mu = 1; mu < 8; mu++) {        // mu=0 twiddle is 1
        r[BR3[mu]]     = cmul(r[BR3[mu]], wp0);
        r[8 + BR3[mu]] = cmul(r[8 + BR3[mu]], wp1);
        wp0 = cmul(wp0, w0);
        wp1 = cmul(wp1, w1);
    }
    // q[k] = slot(mu=t, t_w=k)@lane k (k<8: first half, k>=8: second half)
    cf a[8], b[8];
#pragma unroll
    for (int mu = 0; mu < 8; mu++) { a[mu] = r[BR3[mu]]; b[mu] = r[8 + BR3[mu]]; }
    xpose8(a, t);
    xpose8(b, t);
    cf q[16];
#pragma unroll
    for (int k = 0; k < 8; k++) { q[k] = a[k]; q[8 + k] = b[k]; }
    dft16<SGN>(q);       // z[t + 8*m1] = q[BR4[m1]]
#pragma unroll
    for (int m1 = 0; m1 < 16; m1++) o[m1] = q[BR4[m1]];
}

__global__ __launch_bounds__(1024) __attribute__((amdgpu_waves_per_eu(4, 4)))
void operators_52261162057769_kernel(
        const float* __restrict__ x, const float* __restrict__ df,
        const float* __restrict__ d2f, float* __restrict__ out,
        long outn, int nch) {
    extern __shared__ float lds[];
    float* Mre = lds;
    float* Mim = lds + 128 * LSTR;

    const int tid = threadIdx.x;
    const int g = tid >> 3;     // row (R-phases) / column (C-phases) id
    const int t = tid & 7;      // lane within 8-thread FFT group
    const int im = blockIdx.x;
    const int ch = im % nch;
    const long base = (long)im * 16384L;

    float* out_h  = out;
    float* out_la = out + outn;
    float* out_ph = out + 2 * outn;
    float* out_lt = out + 3 * outn;   // staging: dx.re -> final lnTau
    float* out_ps = out + 4 * outn;   // staging: dx.im -> final Psi

    cf r[16], o[16];

    // ---- Phase R1: forward FFT along rows -> H in LDS ----
#pragma unroll
    for (int j = 0; j < 16; j++) {
        r[j].re = x[base + g * 128 + 8 * j + t];
        r[j].im = 0.f;
    }
    fft128A<-1>(r, o, t);
#pragma unroll
    for (int i = 0; i < 16; i++) {
        int col = t + 8 * (i >> 3) + 16 * (i & 7);
        Mre[g * LSTR + col] = o[i].re;
        Mim[g * LSTR + col] = o[i].im;
    }
    __syncthreads();

    // ---- Phase C1: col c: fwd FFT, * W/16384, inv FFT -> B1 col in LDS ----
    const int c = g;
    const float kc = (c < 64) ? (float)c : (float)(c - 128);
#pragma unroll
    for (int j = 0; j < 16; j++) {
        int a0 = (8 * j + t) * LSTR + c;
        r[j] = { Mre[a0], Mim[a0] };
    }
    fft128A<-1>(r, o, t);
#pragma unroll
    for (int i = 0; i < 16; i++) {
        int d = i >> 3, k2 = i & 7;
        int k = t + 8 * d + 16 * k2;
        float kr = (k2 < 4) ? (float)k : (float)(k - 128);  // k>=64 <=> k2>=4
        cf W = { -kc, kr };                                 // i*k_r - k_c
        cf P = cmul(W, o[i]);
        const float invZ = 1.0f / 16384.0f;                 // full ifft2 norm
        o[i] = { P.re * invZ, P.im * invZ };
    }
    fft128B<1>(o, r, t);                 // r = B1 column (natural ownership)
#pragma unroll
    for (int m1 = 0; m1 < 16; m1++) {    // overwrite own (consumed) H column
        int a0 = (8 * m1 + t) * LSTR + c;
        Mre[a0] = r[m1].re; Mim[a0] = r[m1].im;
    }
    __syncthreads();                     // B1 complete in LDS

    // ---- Phase R2a: rows of B1 (read-only) -> dx; outputs 0..2; stash dx ----
#pragma unroll
    for (int j = 0; j < 16; j++) {
        int a0 = g * LSTR + 8 * j + t;
        r[j] = { Mre[a0], Mim[a0] };
    }
    fft128A<1>(r, o, t);                 // o = dx

    {   // params needed here: dfc only (recomputed later for ep2)
        const float df0 = df[2 * ch], df1 = df[2 * ch + 1];
        const float ea = expf(df0);
        const cf dfc = { ea * cosf(df1), ea * sinf(df1) };
#pragma unroll
        for (int i = 0; i < 16; i++) {
            int col = t + 8 * (i >> 3) + 16 * (i & 7);
            long idx = base + g * 128 + col;
            float xr = o[i].re, xi = o[i].im;
            float h = xr * xr + xi * xi;
            out_h[idx] = h;
            bool valid = sqrtf(h) >= 0.001f;
            float sxr = valid ? xr : 1.f;
            float sxi = valid ? xi : 0.f;
            float hs  = valid ? h : 1.f;
            float ih  = 1.f / hs;
            // a2 = dfc * conj(dxs) / |dxs|^2
            float a2r = (dfc.re * sxr + dfc.im * sxi) * ih;
            float a2i = (dfc.im * sxr - dfc.re * sxi) * ih;
            float la = 0.5f * __logf(a2r * a2r + a2i * a2i);
            la = fminf(fmaxf(la, -3.f), 3.f);
            out_la[idx] = valid ? la : 0.f;
            float ph = atan2f(a2i, a2r);
            out_ph[idx] = valid ? ph : 0.f;
            out_lt[idx] = xr;            // stash dx (overwritten in ep2)
            out_ps[idx] = xi;
        }
    }
    __syncthreads();   // R2a LDS reads done before C2 overwrites columns
                       // (also drains stash stores: vmcnt(0) before barrier)

    // ---- Phase C2: col c of B1: fwd FFT (=W*F/128), * W/128, inv -> B2 ----
#pragma unroll
    for (int j = 0; j < 16; j++) {
        int a0 = (8 * j + t) * LSTR + c;
        r[j] = { Mre[a0], Mim[a0] };
    }
    fft128A<-1>(r, o, t);                // o = FFT0(B1) = W*F/128
#pragma unroll
    for (int i = 0; i < 16; i++) {
        int d = i >> 3, k2 = i & 7;
        int k = t + 8 * d + 16 * k2;
        float kr = (k2 < 4) ? (float)k : (float)(k - 128);
        cf W = { -kc, kr };
        cf P = cmul(W, o[i]);
        const float s = 1.0f / 128.0f;   // restore ifft2 norm for this pass
        o[i] = { P.re * s, P.im * s };
    }
    fft128B<1>(o, r, t);                 // r = B2 column
#pragma unroll
    for (int m1 = 0; m1 < 16; m1++) {
        int a0 = (8 * m1 + t) * LSTR + c;
        Mre[a0] = r[m1].re; Mim[a0] = r[m1].im;
    }
    __syncthreads();                     // B2 complete in LDS

    // ---- Phase R2b: rows of B2 -> dy; reload dx stash; outputs 3..4 ----
#pragma unroll
    for (int j = 0; j < 16; j++) {
        int a0 = g * LSTR + 8 * j + t;
        r[j] = { Mre[a0], Mim[a0] };
    }
    fft128A<1>(r, o, t);                 // o = dy

    {   // params for ep2
        const float df0 = df[2 * ch], df1 = df[2 * ch + 1];
        const float ea = expf(df0);
        const cf dfc = { ea * cosf(df1), ea * sinf(df1) };
        const cf d2fc = { d2f[2 * ch], d2f[2 * ch + 1] };
        const cf df2 = cmul(dfc, dfc);
        const float df2m = 1.0f / (df2.re * df2.re + df2.im * df2.im);
        const cf inv_df2 = { df2.re * df2m, -df2.im * df2m };   // 1/dfc^2
#pragma unroll
        for (int i = 0; i < 16; i++) {
            int col = t + 8 * (i >> 3) + 16 * (i & 7);
            long idx = base + g * 128 + col;
            float xr = out_lt[idx];      // dx stash (same thread wrote it;
            float xi = out_ps[idx];      //  two vmcnt(0)+barriers since)
            float yr = o[i].re, yi = o[i].im;
            float h = xr * xr + xi * xi;
            bool valid = sqrtf(h) >= 0.001f;
            float sxr = valid ? xr : 1.f;
            float sxi = valid ? xi : 0.f;
            float hs  = valid ? h : 1.f;
            float ih  = 1.f / hs;
            // w2 = dxs^2
            float w2r = sxr * sxr - sxi * sxi;
            float w2i = 2.f * sxr * sxi;
            // an = 0.5*(d2x0 - d2fc*w2/dfc^2) * dfc * conj(w2) / hs^2
            cf t1 = cmul(d2fc, { w2r, w2i });
            cf u  = cmul(t1, inv_df2);
            cf v  = { yr - u.re, yi - u.im };
            cf t2 = cmul(v, dfc);
            cf t3 = cmul(t2, { w2r, -w2i });
            float s = 0.5f * ih * ih;
            float anr = t3.re * s, ani = t3.im * s;
            float m2 = anr * anr + ani * ani;
            bool tm = valid && (sqrtf(m2) >= 0.001f);
            float lt = 0.5f * __logf(m2);
            lt = fminf(fmaxf(lt, -2.5902671654f), 3.f);
            out_lt[idx] = tm ? lt : -6.9077552790f;
            float ps = atan2f(ani, anr);
            out_ps[idx] = tm ? ps : 0.f;
        }
    }
}

extern "C" void kernel_launch(void* const* d_in, const int* in_sizes, int n_in,
                              void* d_out, int out_size, void* d_ws, size_t ws_size,
                              hipStream_t stream) {
    const float* x   = (const float*)d_in[0];
    const float* df  = (const float*)d_in[1];
    const float* d2f = (const float*)d_in[2];
    float* out = (float*)d_out;

    const int n_img = in_sizes[0] / 16384;       // b*C = 1024
    const int nch   = in_sizes[1] / 2;           // C = 64
    const long outn = (long)out_size / 5;

    // >64KB dynamic LDS needs the attribute; host-side, graph-capture safe.
    hipFuncSetAttribute((const void*)operators_52261162057769_kernel,
                        hipFuncAttributeMaxDynamicSharedMemorySize, SHBYTES);

    operators_52261162057769_kernel<<<dim3(n_img), dim3(1024), SHBYTES, stream>>>(
        x, df, d2f, out, outn, nch);
}

// Round 3
// 693.660 us; speedup vs baseline: 1.7125x; 1.6217x over previous
//
#include <hip/hip_runtime.h>
#include <math.h>

// Fused spectral Wirtinger-derivative kernel, v4: 16-thread FFTs, two launches.
//
// Hard constraint learned in R0-R2: the compiler pins this kernel at 64 VGPRs
// (dynamic-LDS kernels ignore launch_bounds/waves_per_eu here); any design
// holding ~32+ data floats per thread spills ~1GB/dispatch. So:
//  * 128-pt FFT = 16 threads x 8 cf (was 8 x 16). Peak live ~20 data floats.
//  * Exchange through the row/column's OWN LDS storage (dead during the FFT),
//    wave-contained (16 | 64) -> no __syncthreads inside FFTs, 2 per launch.
//  * Two launches (mode 0/1) so only ONE intermediate image ever exists:
//      mode 0: R1 fwd rows -> C1 (xW/16384, inv) -> B1 -> R2 inv rows -> dx
//              -> outputs h/lnAlpha/Phi, stash dx in out_lt/out_ps.
//      mode 1: R1 fwd rows (recompute) -> C2 (xW^2/16384, inv) -> B2 -> R2 inv
//              rows -> dy; reload dx stash; outputs lnTau/Psi.
//    Stream-ordered dispatches give cross-launch stash coherence.

#define LSTRC 130                      // LDS row stride in cf (float2) units
#define SHBYTES (128 * LSTRC * 8)      // 133120 B

struct cf { float re, im; };
__device__ __forceinline__ cf cmul(cf a, cf b) {
    return { a.re * b.re - a.im * b.im, a.re * b.im + a.im * b.re };
}
__device__ __forceinline__ cf cadd(cf a, cf b) { return { a.re + b.re, a.im + b.im }; }
__device__ __forceinline__ cf csub(cf a, cf b) { return { a.re - b.re, a.im - b.im }; }

__device__ constexpr int BR3[8] = {0,4,2,6,1,5,3,7};

// 8-point DFT, radix-2 DIF, natural in, bit-reversed out: R[k] = r[BR3[k]],
// R[k] = sum_j r[j] e^{SGN*2pi i jk/8}.  (verified in R0-R2 harness runs)
template <int SGN>
__device__ __forceinline__ void dft8(cf* r) {
    const float C8[4] = {1.f, 0.70710678119f, 0.f, -0.70710678119f};
    const float S8[4] = {0.f, 0.70710678119f, 1.f, 0.70710678119f};
#pragma unroll
    for (int j = 0; j < 4; j++) {
        cf u = r[j], v = r[j + 4];
        r[j] = cadd(u, v);
        cf d = csub(u, v);
        cf w = { C8[j], (float)SGN * S8[j] };
        r[j + 4] = cmul(d, w);
    }
#pragma unroll
    for (int b = 0; b < 8; b += 4) {
        cf u = r[b], v = r[b + 2];
        r[b] = cadd(u, v); r[b + 2] = csub(u, v);
        u = r[b + 1]; v = r[b + 3];
        r[b + 1] = cadd(u, v);
        cf d = csub(u, v);
        r[b + 3] = { (float)(-SGN) * d.im, (float)SGN * d.re };
    }
#pragma unroll
    for (int b = 0; b < 8; b += 2) {
        cf u = r[b], v = r[b + 1];
        r[b] = cadd(u, v); r[b + 1] = csub(u, v);
    }
}

// ---- 128-pt FFT, 16 threads (u = 0..15), 8 cf per thread. ----
// Decomposition 128 = 8x16: X[m + 8s] = sum_t W128^{t(m+8s)} Y_t[m],
// Y_t[m] = 8-pt DFT of x[t+16j].  Exchange slot(t,m) = 8t + (m ^ (t&7))
// (XOR spreads banks), placed at M[base + slot*stride] (the row/col's own
// storage; its data is already in registers).  Wave-contained: no barrier.
//
// Variant A: natural in (r[j] = x[u+16j]) -> A-form out (r[s] = X[rho+16s],
// rho = (u>>1) | ((u&1)<<3)).
template <int SGN>
__device__ __forceinline__ void fftA(cf* r, int u, cf* M, int base, int stride) {
    dft8<SGN>(r);                       // Y[m] at r[BR3[m]]
    float sv, cv;
    __sincosf(6.283185307179586f * (float)u * (1.0f / 128.0f), &sv, &cv);
    cf w = { cv, (float)SGN * sv };     // T^u, T = e^{SGN 2pi i/128}
    cf wp = w;
#pragma unroll
    for (int m = 1; m < 8; m++) {       // twiddle T^{u*m}
        r[BR3[m]] = cmul(r[BR3[m]], wp);
        wp = cmul(wp, w);
    }
#pragma unroll
    for (int m = 0; m < 8; m++) {
        int slot = 8 * u + (m ^ (u & 7));
        M[base + slot * stride] = r[BR3[m]];
    }
    asm volatile("s_waitcnt lgkmcnt(0)" ::: "memory");
    // 16-pt DFT over t, split radix-2 DIF across the thread pair (2m, 2m+1):
    // even outputs <- 8-pt DFT of (c_t + c_{t+8}); odd <- of (c_t - c_{t+8})*w16^t.
    const int ms = u >> 1, h = u & 1;
    const float CW16[8] = {1.f, 0.92387953251f, 0.70710678119f, 0.38268343236f,
                           0.f, -0.38268343236f, -0.70710678119f, -0.92387953251f};
    const float SW16[8] = {0.f, 0.38268343236f, 0.70710678119f, 0.92387953251f,
                           1.f, 0.92387953251f, 0.70710678119f, 0.38268343236f};
    cf e[8];
#pragma unroll
    for (int j = 0; j < 8; j++) {
        cf d0 = M[base + (8 * j + (ms ^ j)) * stride];          // c_j
        cf d1 = M[base + (64 + 8 * j + (ms ^ j)) * stride];     // c_{j+8}
        cf s  = cadd(d0, d1);
        cf df_ = csub(d0, d1);
        cf w16 = { CW16[j], (float)SGN * SW16[j] };
        cf v  = cmul(df_, w16);
        e[j].re = h ? v.re : s.re;
        e[j].im = h ? v.im : s.im;
    }
    dft8<SGN>(e);                       // Z at e[BR3[s]]
#pragma unroll
    for (int s = 0; s < 8; s++) r[s] = e[BR3[s]];   // r[s] = X[rho + 16s]
}

// Variant B: A-form in (r[s] = Y[rho+16s]) -> natural out (r[j] = z[u+16j]).
// z[u+16j] = sum_{p<8} e^{SGN 2pi i j p/8} C[p],
// C[p] = T^{u p} (D_p[u&7] + w16^u D_{p+8}[u&7]),  D_rho = 8-pt DFT over s.
template <int SGN>
__device__ __forceinline__ void fftB(cf* r, int u, cf* M, int base, int stride) {
    dft8<SGN>(r);                       // D[m] at r[BR3[m]]
    const int rho = (u >> 1) | ((u & 1) << 3);
#pragma unroll
    for (int m = 0; m < 8; m++) {
        int slot = 8 * rho + (m ^ (rho & 7));
        M[base + slot * stride] = r[BR3[m]];
    }
    asm volatile("s_waitcnt lgkmcnt(0)" ::: "memory");
    const int ms = u & 7;
    float sv, cv;
    __sincosf(6.283185307179586f * (float)u * (1.0f / 128.0f), &sv, &cv);
    cf w = { cv, (float)SGN * sv };     // T^u
    __sincosf(6.283185307179586f * (float)u * (1.0f / 16.0f), &sv, &cv);
    cf w16u = { cv, (float)SGN * sv };  // e^{SGN 2pi i u/16}
    cf C[8];
    cf wp = { 1.f, 0.f };
#pragma unroll
    for (int p = 0; p < 8; p++) {
        cf d0 = M[base + (8 * p + (ms ^ p)) * stride];          // D_p[ms]
        cf d1 = M[base + (64 + 8 * p + (ms ^ p)) * stride];     // D_{p+8}[ms]
        cf t = cadd(d0, cmul(w16u, d1));
        C[p] = (p == 0) ? t : cmul(wp, t);
        wp = cmul(wp, w);
    }
    dft8<SGN>(C);
#pragma unroll
    for (int j = 0; j < 8; j++) r[j] = C[BR3[j]];   // r[j] = z[u+16j]
}

__global__ __launch_bounds__(1024) void operators_52261162057769_kernel(
        const float* __restrict__ x, const float* __restrict__ df,
        const float* __restrict__ d2f, float* __restrict__ out,
        long outn, int nch, int mode) {
    extern __shared__ float ldsraw[];
    cf* M = (cf*)ldsraw;

    const int tid = threadIdx.x;
    const int gg = tid >> 4;            // group 0..63 (wave-contained: 16|64)
    const int u  = tid & 15;
    const int rho = (u >> 1) | ((u & 1) << 3);
    const int im = blockIdx.x;
    const int ch = im % nch;
    const long base = (long)im * 16384L;

    float* out_h  = out;
    float* out_la = out + outn;
    float* out_ph = out + 2 * outn;
    float* out_lt = out + 3 * outn;     // mode0: stash dx.re ; mode1: lnTau
    float* out_ps = out + 4 * outn;     // mode0: stash dx.im ; mode1: Psi

    cf r[8];

    // ---- R1: forward FFT along rows -> H (freq cols) in LDS ----
#pragma unroll
    for (int rr = 0; rr < 2; rr++) {
        int row = gg + 64 * rr;
#pragma unroll
        for (int j = 0; j < 8; j++) {
            r[j].re = x[base + row * 128 + u + 16 * j];
            r[j].im = 0.f;
        }
        fftA<-1>(r, u, M, row * LSTRC, 1);
#pragma unroll
        for (int s = 0; s < 8; s++)      // store at true freq positions
            M[row * LSTRC + rho + 16 * s] = r[s];
    }
    __syncthreads();

    // ---- C: per column c: fwd FFT, * (W or W^2)/16384, inv FFT -> LDS ----
    const float invZ = 1.0f / 16384.0f;
#pragma unroll
    for (int rr = 0; rr < 2; rr++) {
        int c = gg + 64 * rr;
        float kcv = (c < 64) ? (float)c : (float)(c - 128);
#pragma unroll
        for (int j = 0; j < 8; j++) r[j] = M[(u + 16 * j) * LSTRC + c];
        fftA<-1>(r, u, M, c, LSTRC);
#pragma unroll
        for (int s = 0; s < 8; s++) {
            int k = rho + 16 * s;
            float krv = (s < 4) ? (float)k : (float)(k - 128);
            cf W = { -kcv, krv };                 // i*k_r - k_c
            cf P = cmul(W, r[s]);
            if (mode) P = cmul(W, P);             // W^2 for d2x0 pass
            r[s] = { P.re * invZ, P.im * invZ };
        }
        fftB<1>(r, u, M, c, LSTRC);
#pragma unroll
        for (int j = 0; j < 8; j++) M[(u + 16 * j) * LSTRC + c] = r[j];
    }
    __syncthreads();

    // ---- R2: inverse FFT along rows -> derivative; epilogue ----
#pragma unroll
    for (int rr = 0; rr < 2; rr++) {
        int row = gg + 64 * rr;
#pragma unroll
        for (int j = 0; j < 8; j++) r[j] = M[row * LSTRC + u + 16 * j];
        fftA<1>(r, u, M, row * LSTRC, 1);        // r[s] = deriv at col rho+16s

        if (mode == 0) {
            const float df0 = df[2 * ch], df1 = df[2 * ch + 1];
            const float ea = expf(df0);
            const cf dfc = { ea * cosf(df1), ea * sinf(df1) };
#pragma unroll
            for (int s = 0; s < 8; s++) {
                long idx = base + row * 128 + rho + 16 * s;
                float xr = r[s].re, xi = r[s].im;
                float h = xr * xr + xi * xi;
                out_h[idx] = h;
                bool valid = sqrtf(h) >= 0.001f;
                float sxr = valid ? xr : 1.f;
                float sxi = valid ? xi : 0.f;
                float hs  = valid ? h : 1.f;
                float ih  = 1.f / hs;
                // a2 = dfc * conj(dxs) / |dxs|^2
                float a2r = (dfc.re * sxr + dfc.im * sxi) * ih;
                float a2i = (dfc.im * sxr - dfc.re * sxi) * ih;
                float la = 0.5f * __logf(a2r * a2r + a2i * a2i);
                la = fminf(fmaxf(la, -3.f), 3.f);
                out_la[idx] = valid ? la : 0.f;
                float ph = atan2f(a2i, a2r);
                out_ph[idx] = valid ? ph : 0.f;
                out_lt[idx] = xr;                // stash dx for launch 2
                out_ps[idx] = xi;
            }
        } else {
            const float df0 = df[2 * ch], df1 = df[2 * ch + 1];
            const float ea = expf(df0);
            const cf dfc = { ea * cosf(df1), ea * sinf(df1) };
            const cf d2fc = { d2f[2 * ch], d2f[2 * ch + 1] };
            const cf df2 = cmul(dfc, dfc);
            const float df2m = 1.0f / (df2.re * df2.re + df2.im * df2.im);
            const cf inv_df2 = { df2.re * df2m, -df2.im * df2m };
#pragma unroll
            for (int s = 0; s < 8; s++) {
                long idx = base + row * 128 + rho + 16 * s;
                float xr = out_lt[idx];          // dx stash from launch 1
                float xi = out_ps[idx];
                float yr = r[s].re, yi = r[s].im;
                float h = xr * xr + xi * xi;
                bool valid = sqrtf(h) >= 0.001f;
                float sxr = valid ? xr : 1.f;
                float sxi = valid ? xi : 0.f;
                float hs  = valid ? h : 1.f;
                float ih  = 1.f / hs;
                float w2r = sxr * sxr - sxi * sxi;
                float w2i = 2.f * sxr * sxi;
                cf t1 = cmul(d2fc, { w2r, w2i });
                cf uu = cmul(t1, inv_df2);
                cf v  = { yr - uu.re, yi - uu.im };
                cf t2 = cmul(v, dfc);
                cf t3 = cmul(t2, { w2r, -w2i });
                float sc = 0.5f * ih * ih;
                float anr = t3.re * sc, ani = t3.im * sc;
                float m2 = anr * anr + ani * ani;
                bool tm = valid && (sqrtf(m2) >= 0.001f);
                float lt = 0.5f * __logf(m2);
                lt = fminf(fmaxf(lt, -2.5902671654f), 3.f);
                out_lt[idx] = tm ? lt : -6.9077552790f;
                float ps = atan2f(ani, anr);
                out_ps[idx] = tm ? ps : 0.f;
            }
        }
    }
}

extern "C" void kernel_launch(void* const* d_in, const int* in_sizes, int n_in,
                              void* d_out, int out_size, void* d_ws, size_t ws_size,
                              hipStream_t stream) {
    const float* x   = (const float*)d_in[0];
    const float* df  = (const float*)d_in[1];
    const float* d2f = (const float*)d_in[2];
    float* out = (float*)d_out;

    const int n_img = in_sizes[0] / 16384;       // b*C = 1024
    const int nch   = in_sizes[1] / 2;           // C = 64
    const long outn = (long)out_size / 5;

    hipFuncSetAttribute((const void*)operators_52261162057769_kernel,
                        hipFuncAttributeMaxDynamicSharedMemorySize, SHBYTES);

    // Launch 1: dx pass (h, lnAlpha, Phi; stash dx).  Launch 2: d2x0 pass
    // (lnTau, Psi from stash).  Stream order gives stash coherence.
    operators_52261162057769_kernel<<<dim3(n_img), dim3(1024), SHBYTES, stream>>>(
        x, df, d2f, out, outn, nch, 0);
    operators_52261162057769_kernel<<<dim3(n_img), dim3(1024), SHBYTES, stream>>>(
        x, df, d2f, out, outn, nch, 1);
}